// Round 1
// baseline (879.964 us; speedup 1.0000x reference)
//
#include <hip/hip_runtime.h>
#include <math.h>

// GCN ValueNet forward, fp32 baseline.
// Pipeline per layer L with weight W [K,M]:
//   H = X @ W                      (gemm_rows / gemm_k64_m1)
//   A = scatter_e H[src]*dinv[src]*dinv[dst] -> dst   (agg_edges, atomicAdd)
//   A = tanh(A + H*selfnorm + b)   (self_tanh)
// Degrees/dinv computed once (graph shared across layers).

constexpr int BLOCK = 256;

__global__ void deg_kernel(const int* __restrict__ dst, float* __restrict__ deg, int E) {
    int e = blockIdx.x * blockDim.x + threadIdx.x;
    if (e < E) atomicAdd(&deg[dst[e]], 1.0f);
}

__global__ void dinv_kernel(float* __restrict__ degv, float* __restrict__ selfn, int N) {
    int i = blockIdx.x * blockDim.x + threadIdx.x;
    if (i < N) {
        float d = degv[i] + 1.0f;      // +1 self loop
        float di = 1.0f / sqrtf(d);
        degv[i] = di;                   // becomes dinv
        selfn[i] = di * di;             // self-loop norm = 1/deg
    }
}

// One block per node row; blockDim == M. H[n,f] = sum_k X[n,k]*W[k,f]  (NO bias here —
// reference adds bias after aggregation).
template<int K, int M>
__global__ void gemm_rows(const float* __restrict__ X, const float* __restrict__ W,
                          float* __restrict__ H, int N) {
    __shared__ float xs[K];
    int n = blockIdx.x;
    for (int k = threadIdx.x; k < K; k += M) xs[k] = X[(size_t)n * K + k];
    __syncthreads();
    int f = threadIdx.x;
    float acc = 0.0f;
#pragma unroll 16
    for (int k = 0; k < K; ++k) acc = fmaf(xs[k], W[k * M + f], acc);
    H[(size_t)n * M + f] = acc;
}

// K=64, M=1: one 64-lane wave per node, shuffle-reduce the dot product.
__global__ void gemm_k64_m1(const float* __restrict__ X, const float* __restrict__ W,
                            float* __restrict__ H, int N) {
    int gtid = blockIdx.x * blockDim.x + threadIdx.x;
    int n = gtid >> 6;
    int lane = threadIdx.x & 63;
    if (n >= N) return;
    float v = X[(size_t)n * 64 + lane] * W[lane];
#pragma unroll
    for (int off = 32; off > 0; off >>= 1) v += __shfl_down(v, off);
    if (lane == 0) H[n] = v;
}

// Edge scatter: thread (e,f) does A[dst[e],f] += H[src[e],f] * dinv[src]*dinv[dst].
template<int M>
__global__ void __launch_bounds__(BLOCK) agg_edges(const int* __restrict__ src,
                                                   const int* __restrict__ dst,
                                                   const float* __restrict__ dinv,
                                                   const float* __restrict__ H,
                                                   float* __restrict__ A, int E) {
    long long idx = (long long)blockIdx.x * blockDim.x + threadIdx.x;
    int e = (int)(idx / M);
    int f = (int)(idx - (long long)e * M);
    if (e >= E) return;
    int s = src[e], d = dst[e];
    float norm = dinv[s] * dinv[d];
    atomicAdd(&A[(size_t)d * M + f], H[(size_t)s * M + f] * norm);
}

// A[n,f] = tanh(A[n,f] + H[n,f]*selfnorm[n] + b[f])
template<int M>
__global__ void self_tanh(const float* __restrict__ H, const float* __restrict__ selfn,
                          const float* __restrict__ bias, float* __restrict__ A, int N) {
    long long idx = (long long)blockIdx.x * blockDim.x + threadIdx.x;
    int n = (int)(idx / M);
    int f = (int)(idx - (long long)n * M);
    if (n >= N) return;
    float v = A[idx] + H[idx] * selfn[n] + bias[f];
    A[idx] = tanhf(v);
}

__global__ void dot_reduce(const float* __restrict__ h, const float* __restrict__ w,
                           float* __restrict__ partials, int N) {
    float acc = 0.0f;
    for (int i = blockIdx.x * blockDim.x + threadIdx.x; i < N; i += gridDim.x * blockDim.x)
        acc += h[i] * w[i];
#pragma unroll
    for (int off = 32; off > 0; off >>= 1) acc += __shfl_down(acc, off);
    __shared__ float sm[4];
    int lane = threadIdx.x & 63, wid = threadIdx.x >> 6;
    if (lane == 0) sm[wid] = acc;
    __syncthreads();
    if (threadIdx.x == 0) partials[blockIdx.x] = sm[0] + sm[1] + sm[2] + sm[3];
}

__global__ void final_sum(const float* __restrict__ partials, int B,
                          const float* __restrict__ b4, float* __restrict__ out) {
    float acc = 0.0f;
    for (int i = threadIdx.x; i < B; i += blockDim.x) acc += partials[i];
#pragma unroll
    for (int off = 32; off > 0; off >>= 1) acc += __shfl_down(acc, off);
    __shared__ float sm[4];
    int lane = threadIdx.x & 63, wid = threadIdx.x >> 6;
    if (lane == 0) sm[wid] = acc;
    __syncthreads();
    if (threadIdx.x == 0) out[0] = sm[0] + sm[1] + sm[2] + sm[3] + b4[0];
}

extern "C" void kernel_launch(void* const* d_in, const int* in_sizes, int n_in,
                              void* d_out, int out_size, void* d_ws, size_t ws_size,
                              hipStream_t stream) {
    const float* x  = (const float*)d_in[0];
    const int*   ei = (const int*)d_in[1];
    const float* W1 = (const float*)d_in[2];
    const float* b1 = (const float*)d_in[3];
    const float* W2 = (const float*)d_in[4];
    const float* b2 = (const float*)d_in[5];
    const float* W3 = (const float*)d_in[6];
    const float* b3 = (const float*)d_in[7];
    const float* W4 = (const float*)d_in[8];
    const float* b4 = (const float*)d_in[9];

    const int N = in_sizes[0] / 128;   // 50000
    const int E = in_sizes[1] / 2;     // 800000
    const int* src = ei;
    const int* dst = ei + E;

    // Workspace layout (floats). Peak use ~ (2 + 256)*N + 256 ≈ 51.6 MB.
    float* ws    = (float*)d_ws;
    float* dinv  = ws;                         // N  (deg -> dinv)
    float* selfn = dinv + N;                   // N
    float* bufA  = selfn + N;                  // N*128  (H of current layer)
    float* bufB  = bufA + (size_t)N * 128;     // N*128  (A of current layer / next X)
    float* partials = bufB + (size_t)N * 128;  // 256

    const int nblkN = (N + BLOCK - 1) / BLOCK;
    const int nblkE = (E + BLOCK - 1) / BLOCK;

    // --- degrees ---
    hipMemsetAsync(dinv, 0, (size_t)N * sizeof(float), stream);
    deg_kernel<<<nblkE, BLOCK, 0, stream>>>(dst, dinv, E);
    dinv_kernel<<<nblkN, BLOCK, 0, stream>>>(dinv, selfn, N);

    // --- layer 1: 128 -> 128 ---
    gemm_rows<128, 128><<<N, 128, 0, stream>>>(x, W1, bufA, N);
    hipMemsetAsync(bufB, 0, (size_t)N * 128 * sizeof(float), stream);
    {
        long long tot = (long long)E * 128;
        agg_edges<128><<<(int)((tot + BLOCK - 1) / BLOCK), BLOCK, 0, stream>>>(src, dst, dinv, bufA, bufB, E);
    }
    {
        long long tot = (long long)N * 128;
        self_tanh<128><<<(int)((tot + BLOCK - 1) / BLOCK), BLOCK, 0, stream>>>(bufA, selfn, b1, bufB, N);
    }

    // --- layer 2: 128 -> 64 ---  (input = bufB, H -> bufA, A -> bufB)
    gemm_rows<128, 64><<<N, 64, 0, stream>>>(bufB, W2, bufA, N);
    hipMemsetAsync(bufB, 0, (size_t)N * 64 * sizeof(float), stream);
    {
        long long tot = (long long)E * 64;
        agg_edges<64><<<(int)((tot + BLOCK - 1) / BLOCK), BLOCK, 0, stream>>>(src, dst, dinv, bufA, bufB, E);
    }
    {
        long long tot = (long long)N * 64;
        self_tanh<64><<<(int)((tot + BLOCK - 1) / BLOCK), BLOCK, 0, stream>>>(bufA, selfn, b2, bufB, N);
    }

    // --- layer 3: 64 -> 1 ---
    gemm_k64_m1<<<(N + 3) / 4, BLOCK, 0, stream>>>(bufB, W3, bufA, N);
    hipMemsetAsync(bufB, 0, (size_t)N * sizeof(float), stream);
    agg_edges<1><<<nblkE, BLOCK, 0, stream>>>(src, dst, dinv, bufA, bufB, E);
    self_tanh<1><<<nblkN, BLOCK, 0, stream>>>(bufA, selfn, b3, bufB, N);

    // --- head: out = W4 . h + b4 ---  (two-stage deterministic reduction)
    dot_reduce<<<256, BLOCK, 0, stream>>>(bufB, W4, partials, N);
    final_sum<<<1, BLOCK, 0, stream>>>(partials, 256, b4, (float*)d_out);
}

// Round 2
// 481.550 us; speedup vs baseline: 1.8274x; 1.8274x over previous
//
#include <hip/hip_runtime.h>
#include <math.h>

// GCN ValueNet forward, fp32, CSR-gather aggregation (no fp32 atomics).
// Per layer with weight W [K,M]:
//   Hs = (X @ W) * dinv[n]                      (gemm epilogue fuses scaling)
//   A[d] = tanh( dinv[d]*(Hs[d] + sum_{s in N(d)} Hs[s]) + b )   (agg_csr, fused)
// because norm(s,d) = dinv[s]*dinv[d] and self-norm = dinv[d]^2.
// CSR (rowptr, csr_src by dst) built on-device each call (graph-capture safe).

constexpr int BLOCK = 256;
constexpr int SCAN_B = 256;

__global__ void deg_hist(const int* __restrict__ dst, int* __restrict__ deg, int E) {
    int e = blockIdx.x * blockDim.x + threadIdx.x;
    if (e < E) atomicAdd(&deg[dst[e]], 1);
}

__global__ void dinv_kernel(const int* __restrict__ deg, float* __restrict__ dinv, int N) {
    int i = blockIdx.x * blockDim.x + threadIdx.x;
    if (i < N) dinv[i] = 1.0f / sqrtf((float)deg[i] + 1.0f);  // +1 self loop
}

// Inclusive scan within 256-elem blocks; block totals to bsums.
__global__ void scan_blocks(const int* __restrict__ deg, int* __restrict__ incl,
                            int* __restrict__ bsums, int N) {
    __shared__ int sm[SCAN_B];
    int i = blockIdx.x * SCAN_B + threadIdx.x;
    int v = (i < N) ? deg[i] : 0;
    sm[threadIdx.x] = v;
    __syncthreads();
#pragma unroll
    for (int off = 1; off < SCAN_B; off <<= 1) {
        int t = (threadIdx.x >= off) ? sm[threadIdx.x - off] : 0;
        __syncthreads();
        sm[threadIdx.x] += t;
        __syncthreads();
    }
    if (i < N) incl[i] = sm[threadIdx.x];
    if (threadIdx.x == SCAN_B - 1) bsums[blockIdx.x] = sm[threadIdx.x];
}

// Exclusive scan of block sums (nblk <= 256), in place.
__global__ void scan_partials(int* __restrict__ bsums, int nblk) {
    __shared__ int sm[SCAN_B];
    int v = (threadIdx.x < nblk) ? bsums[threadIdx.x] : 0;
    sm[threadIdx.x] = v;
    __syncthreads();
#pragma unroll
    for (int off = 1; off < SCAN_B; off <<= 1) {
        int t = (threadIdx.x >= off) ? sm[threadIdx.x - off] : 0;
        __syncthreads();
        sm[threadIdx.x] += t;
        __syncthreads();
    }
    if (threadIdx.x < nblk) bsums[threadIdx.x] = sm[threadIdx.x] - v;  // exclusive
}

__global__ void finalize_rowptr(const int* __restrict__ deg, const int* __restrict__ incl,
                                const int* __restrict__ bsums, int* __restrict__ rowptr,
                                int* __restrict__ cursor, int N) {
    int i = blockIdx.x * blockDim.x + threadIdx.x;
    if (i >= N) return;
    int inc = incl[i] + bsums[i / SCAN_B];
    int exc = inc - deg[i];
    rowptr[i] = exc;
    cursor[i] = exc;
    if (i == N - 1) rowptr[N] = inc;
}

__global__ void fill_csr(const int* __restrict__ src, const int* __restrict__ dst,
                         int* __restrict__ cursor, int* __restrict__ csr_src, int E) {
    int e = blockIdx.x * blockDim.x + threadIdx.x;
    if (e < E) {
        int p = atomicAdd(&cursor[dst[e]], 1);
        csr_src[p] = src[e];
    }
}

// One block per node row; blockDim == M. Hs[n,f] = (sum_k X[n,k]*W[k,f]) * dinv[n].
template<int K, int M>
__global__ void gemm_rows(const float* __restrict__ X, const float* __restrict__ W,
                          const float* __restrict__ dinv, float* __restrict__ H, int N) {
    __shared__ float xs[K];
    int n = blockIdx.x;
    for (int k = threadIdx.x; k < K; k += M) xs[k] = X[(size_t)n * K + k];
    __syncthreads();
    int f = threadIdx.x;
    float acc = 0.0f;
#pragma unroll 16
    for (int k = 0; k < K; ++k) acc = fmaf(xs[k], W[k * M + f], acc);
    H[(size_t)n * M + f] = acc * dinv[n];
}

// K=64, M=1: one 64-lane wave per node, shuffle-reduce; epilogue * dinv.
__global__ void gemm_k64_m1(const float* __restrict__ X, const float* __restrict__ W,
                            const float* __restrict__ dinv, float* __restrict__ H, int N) {
    int gtid = blockIdx.x * blockDim.x + threadIdx.x;
    int n = gtid >> 6;
    int lane = threadIdx.x & 63;
    if (n >= N) return;
    float v = X[(size_t)n * 64 + lane] * W[lane];
#pragma unroll
    for (int off = 32; off > 0; off >>= 1) v += __shfl_down(v, off);
    if (lane == 0) H[n] = v * dinv[n];
}

// CSR aggregation, fused self-loop + bias + tanh. One block (M threads) per node.
template<int M>
__global__ void agg_csr(const int* __restrict__ rowptr, const int* __restrict__ csr_src,
                        const float* __restrict__ dinv, const float* __restrict__ Hs,
                        const float* __restrict__ bias, float* __restrict__ A, int N) {
    int n = blockIdx.x;
    int f = threadIdx.x;
    int beg = rowptr[n], end = rowptr[n + 1];
    float acc = Hs[(size_t)n * M + f];          // self contribution (Hs already * dinv[n])
    for (int j = beg; j < end; ++j) {
        int s = csr_src[j];
        acc += Hs[(size_t)s * M + f];
    }
    A[(size_t)n * M + f] = tanhf(acc * dinv[n] + bias[f]);
}

// M=1 variant: one thread per node.
__global__ void agg_csr_m1(const int* __restrict__ rowptr, const int* __restrict__ csr_src,
                           const float* __restrict__ dinv, const float* __restrict__ Hs,
                           const float* __restrict__ bias, float* __restrict__ A, int N) {
    int n = blockIdx.x * blockDim.x + threadIdx.x;
    if (n >= N) return;
    int beg = rowptr[n], end = rowptr[n + 1];
    float acc = Hs[n];
    for (int j = beg; j < end; ++j) acc += Hs[csr_src[j]];
    A[n] = tanhf(acc * dinv[n] + bias[0]);
}

__global__ void dot_reduce(const float* __restrict__ h, const float* __restrict__ w,
                           float* __restrict__ partials, int N) {
    float acc = 0.0f;
    for (int i = blockIdx.x * blockDim.x + threadIdx.x; i < N; i += gridDim.x * blockDim.x)
        acc += h[i] * w[i];
#pragma unroll
    for (int off = 32; off > 0; off >>= 1) acc += __shfl_down(acc, off);
    __shared__ float sm[4];
    int lane = threadIdx.x & 63, wid = threadIdx.x >> 6;
    if (lane == 0) sm[wid] = acc;
    __syncthreads();
    if (threadIdx.x == 0) partials[blockIdx.x] = sm[0] + sm[1] + sm[2] + sm[3];
}

__global__ void final_sum(const float* __restrict__ partials, int B,
                          const float* __restrict__ b4, float* __restrict__ out) {
    float acc = 0.0f;
    for (int i = threadIdx.x; i < B; i += blockDim.x) acc += partials[i];
#pragma unroll
    for (int off = 32; off > 0; off >>= 1) acc += __shfl_down(acc, off);
    __shared__ float sm[4];
    int lane = threadIdx.x & 63, wid = threadIdx.x >> 6;
    if (lane == 0) sm[wid] = acc;
    __syncthreads();
    if (threadIdx.x == 0) out[0] = sm[0] + sm[1] + sm[2] + sm[3] + b4[0];
}

extern "C" void kernel_launch(void* const* d_in, const int* in_sizes, int n_in,
                              void* d_out, int out_size, void* d_ws, size_t ws_size,
                              hipStream_t stream) {
    const float* x  = (const float*)d_in[0];
    const int*   ei = (const int*)d_in[1];
    const float* W1 = (const float*)d_in[2];
    const float* b1 = (const float*)d_in[3];
    const float* W2 = (const float*)d_in[4];
    const float* b2 = (const float*)d_in[5];
    const float* W3 = (const float*)d_in[6];
    const float* b3 = (const float*)d_in[7];
    const float* W4 = (const float*)d_in[8];
    const float* b4 = (const float*)d_in[9];

    const int N = in_sizes[0] / 128;   // 50000
    const int E = in_sizes[1] / 2;     // 800000
    const int* src = ei;
    const int* dst = ei + E;

    const int nscan = (N + SCAN_B - 1) / SCAN_B;   // 196 <= 256

    // Workspace layout (~55.5 MB).
    float* dinv  = (float*)d_ws;               // N
    int* deg     = (int*)(dinv + N);           // N
    int* incl    = deg + N;                    // N
    int* bsums   = incl + N;                   // 256
    int* rowptr  = bsums + 256;                // N+1
    int* cursor  = rowptr + N + 1;             // N
    int* csr_src = cursor + N;                 // E
    float* bufA  = (float*)(csr_src + E);      // N*128
    float* bufB  = bufA + (size_t)N * 128;     // N*128
    float* partials = bufB + (size_t)N * 128;  // 256

    const int nblkN = (N + BLOCK - 1) / BLOCK;
    const int nblkE = (E + BLOCK - 1) / BLOCK;

    // --- degrees + CSR build ---
    hipMemsetAsync(deg, 0, (size_t)N * sizeof(int), stream);
    deg_hist<<<nblkE, BLOCK, 0, stream>>>(dst, deg, E);
    dinv_kernel<<<nblkN, BLOCK, 0, stream>>>(deg, dinv, N);
    scan_blocks<<<nscan, SCAN_B, 0, stream>>>(deg, incl, bsums, N);
    scan_partials<<<1, SCAN_B, 0, stream>>>(bsums, nscan);
    finalize_rowptr<<<nblkN, BLOCK, 0, stream>>>(deg, incl, bsums, rowptr, cursor, N);
    fill_csr<<<nblkE, BLOCK, 0, stream>>>(src, dst, cursor, csr_src, E);

    // --- layer 1: 128 -> 128 ---
    gemm_rows<128, 128><<<N, 128, 0, stream>>>(x, W1, dinv, bufA, N);
    agg_csr<128><<<N, 128, 0, stream>>>(rowptr, csr_src, dinv, bufA, b1, bufB, N);

    // --- layer 2: 128 -> 64 ---
    gemm_rows<128, 64><<<N, 64, 0, stream>>>(bufB, W2, dinv, bufA, N);
    agg_csr<64><<<N, 64, 0, stream>>>(rowptr, csr_src, dinv, bufA, b2, bufB, N);

    // --- layer 3: 64 -> 1 ---
    gemm_k64_m1<<<(N + 3) / 4, BLOCK, 0, stream>>>(bufB, W3, dinv, bufA, N);
    agg_csr_m1<<<nblkN, BLOCK, 0, stream>>>(rowptr, csr_src, dinv, bufA, b3, bufB, N);

    // --- head: out = W4 . h + b4 ---
    dot_reduce<<<256, BLOCK, 0, stream>>>(bufB, W4, partials, N);
    final_sum<<<1, BLOCK, 0, stream>>>(partials, 256, b4, (float*)d_out);
}

// Round 3
// 403.369 us; speedup vs baseline: 2.1815x; 1.1938x over previous
//
#include <hip/hip_runtime.h>
#include <math.h>

// GCN ValueNet forward, fp32, CSR-gather aggregation + register-tiled GEMM.
// Per layer with weight W [K,M]:
//   Hs = (X @ W) * dinv[n]                      (gemm_tiled epilogue fuses scaling)
//   A[d] = tanh( dinv[d]*(Hs[d] + sum_{s in N(d)} Hs[s]) + b )   (agg_csr, fused)
// CSR (rowptr, csr_src by dst) built on-device each call (graph-capture safe).

constexpr int BLOCK = 256;
constexpr int SCAN_B = 256;

__global__ void deg_hist(const int* __restrict__ dst, int* __restrict__ deg, int E) {
    int e = blockIdx.x * blockDim.x + threadIdx.x;
    if (e < E) atomicAdd(&deg[dst[e]], 1);
}

__global__ void dinv_kernel(const int* __restrict__ deg, float* __restrict__ dinv, int N) {
    int i = blockIdx.x * blockDim.x + threadIdx.x;
    if (i < N) dinv[i] = 1.0f / sqrtf((float)deg[i] + 1.0f);  // +1 self loop
}

__global__ void scan_blocks(const int* __restrict__ deg, int* __restrict__ incl,
                            int* __restrict__ bsums, int N) {
    __shared__ int sm[SCAN_B];
    int i = blockIdx.x * SCAN_B + threadIdx.x;
    int v = (i < N) ? deg[i] : 0;
    sm[threadIdx.x] = v;
    __syncthreads();
#pragma unroll
    for (int off = 1; off < SCAN_B; off <<= 1) {
        int t = (threadIdx.x >= off) ? sm[threadIdx.x - off] : 0;
        __syncthreads();
        sm[threadIdx.x] += t;
        __syncthreads();
    }
    if (i < N) incl[i] = sm[threadIdx.x];
    if (threadIdx.x == SCAN_B - 1) bsums[blockIdx.x] = sm[threadIdx.x];
}

__global__ void scan_partials(int* __restrict__ bsums, int nblk) {
    __shared__ int sm[SCAN_B];
    int v = (threadIdx.x < nblk) ? bsums[threadIdx.x] : 0;
    sm[threadIdx.x] = v;
    __syncthreads();
#pragma unroll
    for (int off = 1; off < SCAN_B; off <<= 1) {
        int t = (threadIdx.x >= off) ? sm[threadIdx.x - off] : 0;
        __syncthreads();
        sm[threadIdx.x] += t;
        __syncthreads();
    }
    if (threadIdx.x < nblk) bsums[threadIdx.x] = sm[threadIdx.x] - v;  // exclusive
}

__global__ void finalize_rowptr(const int* __restrict__ deg, const int* __restrict__ incl,
                                const int* __restrict__ bsums, int* __restrict__ rowptr,
                                int* __restrict__ cursor, int N) {
    int i = blockIdx.x * blockDim.x + threadIdx.x;
    if (i >= N) return;
    int inc = incl[i] + bsums[i / SCAN_B];
    int exc = inc - deg[i];
    rowptr[i] = exc;
    cursor[i] = exc;
    if (i == N - 1) rowptr[N] = inc;
}

__global__ void fill_csr(const int* __restrict__ src, const int* __restrict__ dst,
                         int* __restrict__ cursor, int* __restrict__ csr_src, int E) {
    int e = blockIdx.x * blockDim.x + threadIdx.x;
    if (e < E) {
        int p = atomicAdd(&cursor[dst[e]], 1);
        csr_src[p] = src[e];
    }
}

// Register-tiled GEMM: H[n,f] = (sum_k X[n,k]*W[k,f]) * dinv[n].
// 256 threads, 64-row tile. Each thread: TM rows x 4 cols of output.
template<int K, int M>
__global__ void __launch_bounds__(256) gemm_tiled(const float* __restrict__ X,
                                                  const float* __restrict__ W,
                                                  const float* __restrict__ dinv,
                                                  float* __restrict__ H, int N) {
    constexpr int BM = 64;
    constexpr int TN = 4;
    constexpr int TX = M / TN;        // 32 (M=128) or 16 (M=64)
    constexpr int TY = 256 / TX;      // 8 or 16
    constexpr int TM = BM / TY;       // 8 or 4
    constexpr int K4 = K / 4;

    __shared__ float xs[BM][K];       // 64*128*4 = 32 KB

    const int tid = threadIdx.x;
    const int n0 = blockIdx.x * BM;

    // Stage X tile (float4 global loads, b128 LDS writes). Zero-fill OOB rows.
    {
        const float4* X4 = reinterpret_cast<const float4*>(X);
        constexpr int F4_PER_ROW = K / 4;
        constexpr int TOT = BM * F4_PER_ROW;       // 2048 (K=128) / 1024 (K=64)
#pragma unroll
        for (int i = 0; i < TOT / 256; ++i) {
            int idx = tid + i * 256;
            int row = idx / F4_PER_ROW;
            int k4 = idx % F4_PER_ROW;
            float4 v = make_float4(0.f, 0.f, 0.f, 0.f);
            if (n0 + row < N) v = X4[(size_t)(n0 + row) * F4_PER_ROW + k4];
            *reinterpret_cast<float4*>(&xs[row][k4 * 4]) = v;
        }
    }
    __syncthreads();

    const int tx = tid % TX;
    const int ty = tid / TX;
    const int col0 = tx * TN;
    const int row0 = ty * TM;

    float acc[TM][TN];
#pragma unroll
    for (int r = 0; r < TM; ++r)
#pragma unroll
        for (int c = 0; c < TN; ++c) acc[r][c] = 0.0f;

    const float4* W4 = reinterpret_cast<const float4*>(W);
    constexpr int W4_PER_ROW = M / 4;

#pragma unroll 4
    for (int k4 = 0; k4 < K4; ++k4) {
        float4 wv[4];
#pragma unroll
        for (int i = 0; i < 4; ++i)
            wv[i] = W4[(size_t)(k4 * 4 + i) * W4_PER_ROW + tx];
        float4 xv[TM];
#pragma unroll
        for (int r = 0; r < TM; ++r)
            xv[r] = *reinterpret_cast<const float4*>(&xs[row0 + r][k4 * 4]);
#pragma unroll
        for (int r = 0; r < TM; ++r) {
#pragma unroll
            for (int c = 0; c < TN; ++c) {
                float* w0 = (float*)&wv[0];
                acc[r][c] = fmaf(xv[r].x, ((float*)&wv[0])[c], acc[r][c]);
                acc[r][c] = fmaf(xv[r].y, ((float*)&wv[1])[c], acc[r][c]);
                acc[r][c] = fmaf(xv[r].z, ((float*)&wv[2])[c], acc[r][c]);
                acc[r][c] = fmaf(xv[r].w, ((float*)&wv[3])[c], acc[r][c]);
                (void)w0;
            }
        }
    }

    // Epilogue: scale by dinv[row], float4 store.
#pragma unroll
    for (int r = 0; r < TM; ++r) {
        int row = n0 + row0 + r;
        if (row < N) {
            float di = dinv[row];
            float4 o;
            o.x = acc[r][0] * di; o.y = acc[r][1] * di;
            o.z = acc[r][2] * di; o.w = acc[r][3] * di;
            *reinterpret_cast<float4*>(&H[(size_t)row * M + col0]) = o;
        }
    }
}

// K=64, M=1: one 64-lane wave per node, shuffle-reduce; epilogue * dinv.
__global__ void gemm_k64_m1(const float* __restrict__ X, const float* __restrict__ W,
                            const float* __restrict__ dinv, float* __restrict__ H, int N) {
    int gtid = blockIdx.x * blockDim.x + threadIdx.x;
    int n = gtid >> 6;
    int lane = threadIdx.x & 63;
    if (n >= N) return;
    float v = X[(size_t)n * 64 + lane] * W[lane];
#pragma unroll
    for (int off = 32; off > 0; off >>= 1) v += __shfl_down(v, off);
    if (lane == 0) H[n] = v * dinv[n];
}

// CSR aggregation, fused self-loop + bias + tanh. One block (M threads) per node.
template<int M>
__global__ void agg_csr(const int* __restrict__ rowptr, const int* __restrict__ csr_src,
                        const float* __restrict__ dinv, const float* __restrict__ Hs,
                        const float* __restrict__ bias, float* __restrict__ A, int N) {
    int n = blockIdx.x;
    int f = threadIdx.x;
    int beg = rowptr[n], end = rowptr[n + 1];
    float acc = Hs[(size_t)n * M + f];          // self contribution (Hs already * dinv[n])
    for (int j = beg; j < end; ++j) {
        int s = csr_src[j];
        acc += Hs[(size_t)s * M + f];
    }
    A[(size_t)n * M + f] = tanhf(acc * dinv[n] + bias[f]);
}

// M=1 variant: one thread per node.
__global__ void agg_csr_m1(const int* __restrict__ rowptr, const int* __restrict__ csr_src,
                           const float* __restrict__ dinv, const float* __restrict__ Hs,
                           const float* __restrict__ bias, float* __restrict__ A, int N) {
    int n = blockIdx.x * blockDim.x + threadIdx.x;
    if (n >= N) return;
    int beg = rowptr[n], end = rowptr[n + 1];
    float acc = Hs[n];
    for (int j = beg; j < end; ++j) acc += Hs[csr_src[j]];
    A[n] = tanhf(acc * dinv[n] + bias[0]);
}

__global__ void dot_reduce(const float* __restrict__ h, const float* __restrict__ w,
                           float* __restrict__ partials, int N) {
    float acc = 0.0f;
    for (int i = blockIdx.x * blockDim.x + threadIdx.x; i < N; i += gridDim.x * blockDim.x)
        acc += h[i] * w[i];
#pragma unroll
    for (int off = 32; off > 0; off >>= 1) acc += __shfl_down(acc, off);
    __shared__ float sm[4];
    int lane = threadIdx.x & 63, wid = threadIdx.x >> 6;
    if (lane == 0) sm[wid] = acc;
    __syncthreads();
    if (threadIdx.x == 0) partials[blockIdx.x] = sm[0] + sm[1] + sm[2] + sm[3];
}

__global__ void final_sum(const float* __restrict__ partials, int B,
                          const float* __restrict__ b4, float* __restrict__ out) {
    float acc = 0.0f;
    for (int i = threadIdx.x; i < B; i += blockDim.x) acc += partials[i];
#pragma unroll
    for (int off = 32; off > 0; off >>= 1) acc += __shfl_down(acc, off);
    __shared__ float sm[4];
    int lane = threadIdx.x & 63, wid = threadIdx.x >> 6;
    if (lane == 0) sm[wid] = acc;
    __syncthreads();
    if (threadIdx.x == 0) out[0] = sm[0] + sm[1] + sm[2] + sm[3] + b4[0];
}

extern "C" void kernel_launch(void* const* d_in, const int* in_sizes, int n_in,
                              void* d_out, int out_size, void* d_ws, size_t ws_size,
                              hipStream_t stream) {
    const float* x  = (const float*)d_in[0];
    const int*   ei = (const int*)d_in[1];
    const float* W1 = (const float*)d_in[2];
    const float* b1 = (const float*)d_in[3];
    const float* W2 = (const float*)d_in[4];
    const float* b2 = (const float*)d_in[5];
    const float* W3 = (const float*)d_in[6];
    const float* b3 = (const float*)d_in[7];
    const float* W4 = (const float*)d_in[8];
    const float* b4 = (const float*)d_in[9];

    const int N = in_sizes[0] / 128;   // 50000
    const int E = in_sizes[1] / 2;     // 800000
    const int* src = ei;
    const int* dst = ei + E;

    const int nscan = (N + SCAN_B - 1) / SCAN_B;   // 196 <= 256

    // Workspace layout (~55.5 MB).
    float* dinv  = (float*)d_ws;               // N
    int* deg     = (int*)(dinv + N);           // N
    int* incl    = deg + N;                    // N
    int* bsums   = incl + N;                   // 256
    int* rowptr  = bsums + 256;                // N+1
    int* cursor  = rowptr + N + 1;             // N
    int* csr_src = cursor + N;                 // E
    float* bufA  = (float*)(csr_src + E);      // N*128
    float* bufB  = bufA + (size_t)N * 128;     // N*128
    float* partials = bufB + (size_t)N * 128;  // 256

    const int nblkN = (N + BLOCK - 1) / BLOCK;
    const int nblkE = (E + BLOCK - 1) / BLOCK;
    const int ngemm = (N + 63) / 64;

    // --- degrees + CSR build ---
    hipMemsetAsync(deg, 0, (size_t)N * sizeof(int), stream);
    deg_hist<<<nblkE, BLOCK, 0, stream>>>(dst, deg, E);
    dinv_kernel<<<nblkN, BLOCK, 0, stream>>>(deg, dinv, N);
    scan_blocks<<<nscan, SCAN_B, 0, stream>>>(deg, incl, bsums, N);
    scan_partials<<<1, SCAN_B, 0, stream>>>(bsums, nscan);
    finalize_rowptr<<<nblkN, BLOCK, 0, stream>>>(deg, incl, bsums, rowptr, cursor, N);
    fill_csr<<<nblkE, BLOCK, 0, stream>>>(src, dst, cursor, csr_src, E);

    // --- layer 1: 128 -> 128 ---
    gemm_tiled<128, 128><<<ngemm, 256, 0, stream>>>(x, W1, dinv, bufA, N);
    agg_csr<128><<<N, 128, 0, stream>>>(rowptr, csr_src, dinv, bufA, b1, bufB, N);

    // --- layer 2: 128 -> 64 ---
    gemm_tiled<128, 64><<<ngemm, 256, 0, stream>>>(bufB, W2, dinv, bufA, N);
    agg_csr<64><<<N, 64, 0, stream>>>(rowptr, csr_src, dinv, bufA, b2, bufB, N);

    // --- layer 3: 64 -> 1 ---
    gemm_k64_m1<<<(N + 3) / 4, BLOCK, 0, stream>>>(bufB, W3, dinv, bufA, N);
    agg_csr_m1<<<nblkN, BLOCK, 0, stream>>>(rowptr, csr_src, dinv, bufA, b3, bufB, N);

    // --- head: out = W4 . h + b4 ---
    dot_reduce<<<256, BLOCK, 0, stream>>>(bufB, W4, partials, N);
    final_sum<<<1, BLOCK, 0, stream>>>(partials, 256, b4, (float*)d_out);
}

// Round 4
// 366.465 us; speedup vs baseline: 2.4012x; 1.1007x over previous
//
#include <hip/hip_runtime.h>
#include <math.h>

// GCN ValueNet forward, fp32.
// Per layer with weight W [K,M]:
//   Hs = (X @ W) * dinv[n]                      (gemm_tiled epilogue fuses scaling)
//   A[d] = tanh( dinv[d]*(Hs[d] + sum_{s in N(d)} Hs[s]) + b )
// Aggregation = wave-per-node CSR gather: one coalesced load grabs <=64 neighbor
// indices, __shfl broadcasts them (wave-uniform SGPR base), 4 row-gathers in
// flight per unrolled group -> MLP instead of a dependent load chain.
// CSR built on-device each call (graph-capture safe).

constexpr int BLOCK = 256;
constexpr int SCAN_B = 256;

__global__ void deg_hist(const int* __restrict__ dst, int* __restrict__ deg, int E) {
    int e = blockIdx.x * blockDim.x + threadIdx.x;
    if (e < E) atomicAdd(&deg[dst[e]], 1);
}

__global__ void dinv_kernel(const int* __restrict__ deg, float* __restrict__ dinv, int N) {
    int i = blockIdx.x * blockDim.x + threadIdx.x;
    if (i < N) dinv[i] = 1.0f / sqrtf((float)deg[i] + 1.0f);  // +1 self loop
}

__global__ void scan_blocks(const int* __restrict__ deg, int* __restrict__ incl,
                            int* __restrict__ bsums, int N) {
    __shared__ int sm[SCAN_B];
    int i = blockIdx.x * SCAN_B + threadIdx.x;
    int v = (i < N) ? deg[i] : 0;
    sm[threadIdx.x] = v;
    __syncthreads();
#pragma unroll
    for (int off = 1; off < SCAN_B; off <<= 1) {
        int t = (threadIdx.x >= off) ? sm[threadIdx.x - off] : 0;
        __syncthreads();
        sm[threadIdx.x] += t;
        __syncthreads();
    }
    if (i < N) incl[i] = sm[threadIdx.x];
    if (threadIdx.x == SCAN_B - 1) bsums[blockIdx.x] = sm[threadIdx.x];
}

__global__ void scan_partials(int* __restrict__ bsums, int nblk) {
    __shared__ int sm[SCAN_B];
    int v = (threadIdx.x < nblk) ? bsums[threadIdx.x] : 0;
    sm[threadIdx.x] = v;
    __syncthreads();
#pragma unroll
    for (int off = 1; off < SCAN_B; off <<= 1) {
        int t = (threadIdx.x >= off) ? sm[threadIdx.x - off] : 0;
        __syncthreads();
        sm[threadIdx.x] += t;
        __syncthreads();
    }
    if (threadIdx.x < nblk) bsums[threadIdx.x] = sm[threadIdx.x] - v;  // exclusive
}

__global__ void finalize_rowptr(const int* __restrict__ deg, const int* __restrict__ incl,
                                const int* __restrict__ bsums, int* __restrict__ rowptr,
                                int* __restrict__ cursor, int N) {
    int i = blockIdx.x * blockDim.x + threadIdx.x;
    if (i >= N) return;
    int inc = incl[i] + bsums[i / SCAN_B];
    int exc = inc - deg[i];
    rowptr[i] = exc;
    cursor[i] = exc;
    if (i == N - 1) rowptr[N] = inc;
}

__global__ void fill_csr(const int* __restrict__ src, const int* __restrict__ dst,
                         int* __restrict__ cursor, int* __restrict__ csr_src, int E) {
    int e = blockIdx.x * blockDim.x + threadIdx.x;
    if (e < E) {
        int p = atomicAdd(&cursor[dst[e]], 1);
        csr_src[p] = src[e];
    }
}

// Register-tiled GEMM: H[n,f] = (sum_k X[n,k]*W[k,f]) * dinv[n].
template<int K, int M>
__global__ void __launch_bounds__(256) gemm_tiled(const float* __restrict__ X,
                                                  const float* __restrict__ W,
                                                  const float* __restrict__ dinv,
                                                  float* __restrict__ H, int N) {
    constexpr int BM = 64;
    constexpr int TN = 4;
    constexpr int TX = M / TN;
    constexpr int TY = 256 / TX;
    constexpr int TM = BM / TY;
    constexpr int K4 = K / 4;

    __shared__ float xs[BM][K];

    const int tid = threadIdx.x;
    const int n0 = blockIdx.x * BM;

    {
        const float4* X4 = reinterpret_cast<const float4*>(X);
        constexpr int F4_PER_ROW = K / 4;
        constexpr int TOT = BM * F4_PER_ROW;
#pragma unroll
        for (int i = 0; i < TOT / 256; ++i) {
            int idx = tid + i * 256;
            int row = idx / F4_PER_ROW;
            int k4 = idx % F4_PER_ROW;
            float4 v = make_float4(0.f, 0.f, 0.f, 0.f);
            if (n0 + row < N) v = X4[(size_t)(n0 + row) * F4_PER_ROW + k4];
            *reinterpret_cast<float4*>(&xs[row][k4 * 4]) = v;
        }
    }
    __syncthreads();

    const int tx = tid % TX;
    const int ty = tid / TX;
    const int col0 = tx * TN;
    const int row0 = ty * TM;

    float acc[TM][TN];
#pragma unroll
    for (int r = 0; r < TM; ++r)
#pragma unroll
        for (int c = 0; c < TN; ++c) acc[r][c] = 0.0f;

    const float4* W4 = reinterpret_cast<const float4*>(W);
    constexpr int W4_PER_ROW = M / 4;

#pragma unroll 4
    for (int k4 = 0; k4 < K4; ++k4) {
        float4 wv[4];
#pragma unroll
        for (int i = 0; i < 4; ++i)
            wv[i] = W4[(size_t)(k4 * 4 + i) * W4_PER_ROW + tx];
        float4 xv[TM];
#pragma unroll
        for (int r = 0; r < TM; ++r)
            xv[r] = *reinterpret_cast<const float4*>(&xs[row0 + r][k4 * 4]);
#pragma unroll
        for (int r = 0; r < TM; ++r) {
#pragma unroll
            for (int c = 0; c < TN; ++c) {
                acc[r][c] = fmaf(xv[r].x, ((float*)&wv[0])[c], acc[r][c]);
                acc[r][c] = fmaf(xv[r].y, ((float*)&wv[1])[c], acc[r][c]);
                acc[r][c] = fmaf(xv[r].z, ((float*)&wv[2])[c], acc[r][c]);
                acc[r][c] = fmaf(xv[r].w, ((float*)&wv[3])[c], acc[r][c]);
            }
        }
    }

#pragma unroll
    for (int r = 0; r < TM; ++r) {
        int row = n0 + row0 + r;
        if (row < N) {
            float di = dinv[row];
            float4 o;
            o.x = acc[r][0] * di; o.y = acc[r][1] * di;
            o.z = acc[r][2] * di; o.w = acc[r][3] * di;
            *reinterpret_cast<float4*>(&H[(size_t)row * M + col0]) = o;
        }
    }
}

// K=64, M=1: one 64-lane wave per node, shuffle-reduce; epilogue * dinv.
__global__ void gemm_k64_m1(const float* __restrict__ X, const float* __restrict__ W,
                            const float* __restrict__ dinv, float* __restrict__ H, int N) {
    int gtid = blockIdx.x * blockDim.x + threadIdx.x;
    int n = gtid >> 6;
    int lane = threadIdx.x & 63;
    if (n >= N) return;
    float v = X[(size_t)n * 64 + lane] * W[lane];
#pragma unroll
    for (int off = 32; off > 0; off >>= 1) v += __shfl_down(v, off);
    if (lane == 0) H[n] = v * dinv[n];
}

// M=128 aggregation: one wave per node, float2 per lane.
__global__ void __launch_bounds__(256) agg_csr128(const int* __restrict__ rowptr,
                                                  const int* __restrict__ csr_src,
                                                  const float* __restrict__ dinv,
                                                  const float* __restrict__ Hs,
                                                  const float* __restrict__ bias,
                                                  float* __restrict__ A, int N) {
    int wid = threadIdx.x >> 6;
    int lane = threadIdx.x & 63;
    int n = blockIdx.x * 4 + wid;
    if (n >= N) return;
    const float2* H2 = reinterpret_cast<const float2*>(Hs);
    int beg = rowptr[n], end = rowptr[n + 1];
    float2 acc = H2[(size_t)n * 64 + lane];   // self (already * dinv[n])
    for (int j0 = beg; j0 < end; j0 += 64) {
        int cnt = min(64, end - j0);
        int idxv = (lane < cnt) ? csr_src[j0 + lane] : 0;
        int j = 0;
        for (; j + 4 <= cnt; j += 4) {
            int s0 = __shfl(idxv, j);
            int s1 = __shfl(idxv, j + 1);
            int s2 = __shfl(idxv, j + 2);
            int s3 = __shfl(idxv, j + 3);
            float2 v0 = H2[(size_t)s0 * 64 + lane];
            float2 v1 = H2[(size_t)s1 * 64 + lane];
            float2 v2 = H2[(size_t)s2 * 64 + lane];
            float2 v3 = H2[(size_t)s3 * 64 + lane];
            acc.x += v0.x + v1.x + v2.x + v3.x;
            acc.y += v0.y + v1.y + v2.y + v3.y;
        }
        for (; j < cnt; ++j) {
            int s = __shfl(idxv, j);
            float2 v = H2[(size_t)s * 64 + lane];
            acc.x += v.x; acc.y += v.y;
        }
    }
    float di = dinv[n];
    float2 b = reinterpret_cast<const float2*>(bias)[lane];
    float2 o;
    o.x = tanhf(acc.x * di + b.x);
    o.y = tanhf(acc.y * di + b.y);
    reinterpret_cast<float2*>(A)[(size_t)n * 64 + lane] = o;
}

// M=64 aggregation: one wave per node, one float per lane.
__global__ void __launch_bounds__(256) agg_csr64(const int* __restrict__ rowptr,
                                                 const int* __restrict__ csr_src,
                                                 const float* __restrict__ dinv,
                                                 const float* __restrict__ Hs,
                                                 const float* __restrict__ bias,
                                                 float* __restrict__ A, int N) {
    int wid = threadIdx.x >> 6;
    int lane = threadIdx.x & 63;
    int n = blockIdx.x * 4 + wid;
    if (n >= N) return;
    int beg = rowptr[n], end = rowptr[n + 1];
    float acc = Hs[(size_t)n * 64 + lane];
    for (int j0 = beg; j0 < end; j0 += 64) {
        int cnt = min(64, end - j0);
        int idxv = (lane < cnt) ? csr_src[j0 + lane] : 0;
        int j = 0;
        for (; j + 4 <= cnt; j += 4) {
            int s0 = __shfl(idxv, j);
            int s1 = __shfl(idxv, j + 1);
            int s2 = __shfl(idxv, j + 2);
            int s3 = __shfl(idxv, j + 3);
            float v0 = Hs[(size_t)s0 * 64 + lane];
            float v1 = Hs[(size_t)s1 * 64 + lane];
            float v2 = Hs[(size_t)s2 * 64 + lane];
            float v3 = Hs[(size_t)s3 * 64 + lane];
            acc += v0 + v1 + v2 + v3;
        }
        for (; j < cnt; ++j) {
            int s = __shfl(idxv, j);
            acc += Hs[(size_t)s * 64 + lane];
        }
    }
    A[(size_t)n * 64 + lane] = tanhf(acc * dinv[n] + bias[lane]);
}

// M=1 aggregation: one wave per node, lanes parallel over neighbors, shfl-reduce.
__global__ void __launch_bounds__(256) agg_csr_m1(const int* __restrict__ rowptr,
                                                  const int* __restrict__ csr_src,
                                                  const float* __restrict__ dinv,
                                                  const float* __restrict__ Hs,
                                                  const float* __restrict__ bias,
                                                  float* __restrict__ A, int N) {
    int wid = threadIdx.x >> 6;
    int lane = threadIdx.x & 63;
    int n = blockIdx.x * 4 + wid;
    if (n >= N) return;
    int beg = rowptr[n], end = rowptr[n + 1];
    float acc = 0.0f;
    for (int j = beg + lane; j < end; j += 64) acc += Hs[csr_src[j]];
#pragma unroll
    for (int off = 32; off > 0; off >>= 1) acc += __shfl_down(acc, off);
    if (lane == 0) A[n] = tanhf((acc + Hs[n]) * dinv[n] + bias[0]);
}

__global__ void dot_reduce(const float* __restrict__ h, const float* __restrict__ w,
                           float* __restrict__ partials, int N) {
    float acc = 0.0f;
    for (int i = blockIdx.x * blockDim.x + threadIdx.x; i < N; i += gridDim.x * blockDim.x)
        acc += h[i] * w[i];
#pragma unroll
    for (int off = 32; off > 0; off >>= 1) acc += __shfl_down(acc, off);
    __shared__ float sm[4];
    int lane = threadIdx.x & 63, wid = threadIdx.x >> 6;
    if (lane == 0) sm[wid] = acc;
    __syncthreads();
    if (threadIdx.x == 0) partials[blockIdx.x] = sm[0] + sm[1] + sm[2] + sm[3];
}

__global__ void final_sum(const float* __restrict__ partials, int B,
                          const float* __restrict__ b4, float* __restrict__ out) {
    float acc = 0.0f;
    for (int i = threadIdx.x; i < B; i += blockDim.x) acc += partials[i];
#pragma unroll
    for (int off = 32; off > 0; off >>= 1) acc += __shfl_down(acc, off);
    __shared__ float sm[4];
    int lane = threadIdx.x & 63, wid = threadIdx.x >> 6;
    if (lane == 0) sm[wid] = acc;
    __syncthreads();
    if (threadIdx.x == 0) out[0] = sm[0] + sm[1] + sm[2] + sm[3] + b4[0];
}

extern "C" void kernel_launch(void* const* d_in, const int* in_sizes, int n_in,
                              void* d_out, int out_size, void* d_ws, size_t ws_size,
                              hipStream_t stream) {
    const float* x  = (const float*)d_in[0];
    const int*   ei = (const int*)d_in[1];
    const float* W1 = (const float*)d_in[2];
    const float* b1 = (const float*)d_in[3];
    const float* W2 = (const float*)d_in[4];
    const float* b2 = (const float*)d_in[5];
    const float* W3 = (const float*)d_in[6];
    const float* b3 = (const float*)d_in[7];
    const float* W4 = (const float*)d_in[8];
    const float* b4 = (const float*)d_in[9];

    const int N = in_sizes[0] / 128;   // 50000
    const int E = in_sizes[1] / 2;     // 800000
    const int* src = ei;
    const int* dst = ei + E;

    const int nscan = (N + SCAN_B - 1) / SCAN_B;

    // Workspace layout (~55.5 MB).
    float* dinv  = (float*)d_ws;               // N
    int* deg     = (int*)(dinv + N);           // N
    int* incl    = deg + N;                    // N
    int* bsums   = incl + N;                   // 256
    int* rowptr  = bsums + 256;                // N+1
    int* cursor  = rowptr + N + 1;             // N
    int* csr_src = cursor + N;                 // E
    float* bufA  = (float*)(csr_src + E);      // N*128
    float* bufB  = bufA + (size_t)N * 128;     // N*128
    float* partials = bufB + (size_t)N * 128;  // 256

    const int nblkN = (N + BLOCK - 1) / BLOCK;
    const int nblkE = (E + BLOCK - 1) / BLOCK;
    const int ngemm = (N + 63) / 64;
    const int nwave = (N + 3) / 4;             // wave-per-node grids

    // --- degrees + CSR build ---
    hipMemsetAsync(deg, 0, (size_t)N * sizeof(int), stream);
    deg_hist<<<nblkE, BLOCK, 0, stream>>>(dst, deg, E);
    dinv_kernel<<<nblkN, BLOCK, 0, stream>>>(deg, dinv, N);
    scan_blocks<<<nscan, SCAN_B, 0, stream>>>(deg, incl, bsums, N);
    scan_partials<<<1, SCAN_B, 0, stream>>>(bsums, nscan);
    finalize_rowptr<<<nblkN, BLOCK, 0, stream>>>(deg, incl, bsums, rowptr, cursor, N);
    fill_csr<<<nblkE, BLOCK, 0, stream>>>(src, dst, cursor, csr_src, E);

    // --- layer 1: 128 -> 128 ---
    gemm_tiled<128, 128><<<ngemm, 256, 0, stream>>>(x, W1, dinv, bufA, N);
    agg_csr128<<<nwave, 256, 0, stream>>>(rowptr, csr_src, dinv, bufA, b1, bufB, N);

    // --- layer 2: 128 -> 64 ---
    gemm_tiled<128, 64><<<ngemm, 256, 0, stream>>>(bufB, W2, dinv, bufA, N);
    agg_csr64<<<nwave, 256, 0, stream>>>(rowptr, csr_src, dinv, bufA, b2, bufB, N);

    // --- layer 3: 64 -> 1 ---
    gemm_k64_m1<<<(N + 3) / 4, BLOCK, 0, stream>>>(bufB, W3, dinv, bufA, N);
    agg_csr_m1<<<nwave, 256, 0, stream>>>(rowptr, csr_src, dinv, bufA, b3, bufB, N);

    // --- head: out = W4 . h + b4 ---
    dot_reduce<<<256, BLOCK, 0, stream>>>(bufB, W4, partials, N);
    final_sum<<<1, BLOCK, 0, stream>>>(partials, 256, b4, (float*)d_out);
}

// Round 6
// 352.272 us; speedup vs baseline: 2.4980x; 1.0403x over previous
//
#include <hip/hip_runtime.h>
#include <math.h>

// GCN ValueNet forward, fp32.
// Per layer with weight W [K,M]:
//   Hs = (X @ W) * dinv[n]                      (gemm_tiled epilogue fuses scaling)
//   A[d] = tanh( dinv[d]*(Hs[d] + sum_{s in N(d)} Hs[s]) + b )
// Aggregation: wave-per-node CSR gather. Lane halves/quarters map to DIFFERENT
// neighbors so each lane does a float4 load (16 B sweet spot). All __shfl ops
// execute under WAVE-UNIFORM exec (divergent-shfl on CDNA reads inactive lanes
// as undefined — that was R4's bug); tails clamp the source lane and predicate
// only the add. CSR built on-device each call (graph-capture safe).

constexpr int BLOCK = 256;
constexpr int SCAN_B = 256;

__global__ void deg_hist(const int* __restrict__ dst, int* __restrict__ deg, int E) {
    int e = blockIdx.x * blockDim.x + threadIdx.x;
    if (e < E) atomicAdd(&deg[dst[e]], 1);
}

__global__ void dinv_kernel(const int* __restrict__ deg, float* __restrict__ dinv, int N) {
    int i = blockIdx.x * blockDim.x + threadIdx.x;
    if (i < N) dinv[i] = 1.0f / sqrtf((float)deg[i] + 1.0f);  // +1 self loop
}

__global__ void scan_blocks(const int* __restrict__ deg, int* __restrict__ incl,
                            int* __restrict__ bsums, int N) {
    __shared__ int sm[SCAN_B];
    int i = blockIdx.x * SCAN_B + threadIdx.x;
    int v = (i < N) ? deg[i] : 0;
    sm[threadIdx.x] = v;
    __syncthreads();
#pragma unroll
    for (int off = 1; off < SCAN_B; off <<= 1) {
        int t = (threadIdx.x >= off) ? sm[threadIdx.x - off] : 0;
        __syncthreads();
        sm[threadIdx.x] += t;
        __syncthreads();
    }
    if (i < N) incl[i] = sm[threadIdx.x];
    if (threadIdx.x == SCAN_B - 1) bsums[blockIdx.x] = sm[threadIdx.x];
}

__global__ void scan_partials(int* __restrict__ bsums, int nblk) {
    __shared__ int sm[SCAN_B];
    int v = (threadIdx.x < nblk) ? bsums[threadIdx.x] : 0;
    sm[threadIdx.x] = v;
    __syncthreads();
#pragma unroll
    for (int off = 1; off < SCAN_B; off <<= 1) {
        int t = (threadIdx.x >= off) ? sm[threadIdx.x - off] : 0;
        __syncthreads();
        sm[threadIdx.x] += t;
        __syncthreads();
    }
    if (threadIdx.x < nblk) bsums[threadIdx.x] = sm[threadIdx.x] - v;  // exclusive
}

__global__ void finalize_rowptr(const int* __restrict__ deg, const int* __restrict__ incl,
                                const int* __restrict__ bsums, int* __restrict__ rowptr,
                                int* __restrict__ cursor, int N) {
    int i = blockIdx.x * blockDim.x + threadIdx.x;
    if (i >= N) return;
    int inc = incl[i] + bsums[i / SCAN_B];
    int exc = inc - deg[i];
    rowptr[i] = exc;
    cursor[i] = exc;
    if (i == N - 1) rowptr[N] = inc;
}

__global__ void fill_csr(const int* __restrict__ src, const int* __restrict__ dst,
                         int* __restrict__ cursor, int* __restrict__ csr_src, int E) {
    int e = blockIdx.x * blockDim.x + threadIdx.x;
    if (e < E) {
        int p = atomicAdd(&cursor[dst[e]], 1);
        csr_src[p] = src[e];
    }
}

// Register-tiled GEMM: H[n,f] = (sum_k X[n,k]*W[k,f]) * dinv[n].
template<int K, int M>
__global__ void __launch_bounds__(256) gemm_tiled(const float* __restrict__ X,
                                                  const float* __restrict__ W,
                                                  const float* __restrict__ dinv,
                                                  float* __restrict__ H, int N) {
    constexpr int BM = 64;
    constexpr int TN = 4;
    constexpr int TX = M / TN;
    constexpr int TY = 256 / TX;
    constexpr int TM = BM / TY;
    constexpr int K4 = K / 4;

    __shared__ float xs[BM][K];

    const int tid = threadIdx.x;
    const int n0 = blockIdx.x * BM;

    {
        const float4* X4 = reinterpret_cast<const float4*>(X);
        constexpr int F4_PER_ROW = K / 4;
        constexpr int TOT = BM * F4_PER_ROW;
#pragma unroll
        for (int i = 0; i < TOT / 256; ++i) {
            int idx = tid + i * 256;
            int row = idx / F4_PER_ROW;
            int k4 = idx % F4_PER_ROW;
            float4 v = make_float4(0.f, 0.f, 0.f, 0.f);
            if (n0 + row < N) v = X4[(size_t)(n0 + row) * F4_PER_ROW + k4];
            *reinterpret_cast<float4*>(&xs[row][k4 * 4]) = v;
        }
    }
    __syncthreads();

    const int tx = tid % TX;
    const int ty = tid / TX;
    const int col0 = tx * TN;
    const int row0 = ty * TM;

    float acc[TM][TN];
#pragma unroll
    for (int r = 0; r < TM; ++r)
#pragma unroll
        for (int c = 0; c < TN; ++c) acc[r][c] = 0.0f;

    const float4* W4 = reinterpret_cast<const float4*>(W);
    constexpr int W4_PER_ROW = M / 4;

#pragma unroll 4
    for (int k4 = 0; k4 < K4; ++k4) {
        float4 wv[4];
#pragma unroll
        for (int i = 0; i < 4; ++i)
            wv[i] = W4[(size_t)(k4 * 4 + i) * W4_PER_ROW + tx];
        float4 xv[TM];
#pragma unroll
        for (int r = 0; r < TM; ++r)
            xv[r] = *reinterpret_cast<const float4*>(&xs[row0 + r][k4 * 4]);
#pragma unroll
        for (int r = 0; r < TM; ++r) {
#pragma unroll
            for (int c = 0; c < TN; ++c) {
                acc[r][c] = fmaf(xv[r].x, ((float*)&wv[0])[c], acc[r][c]);
                acc[r][c] = fmaf(xv[r].y, ((float*)&wv[1])[c], acc[r][c]);
                acc[r][c] = fmaf(xv[r].z, ((float*)&wv[2])[c], acc[r][c]);
                acc[r][c] = fmaf(xv[r].w, ((float*)&wv[3])[c], acc[r][c]);
            }
        }
    }

#pragma unroll
    for (int r = 0; r < TM; ++r) {
        int row = n0 + row0 + r;
        if (row < N) {
            float di = dinv[row];
            float4 o;
            o.x = acc[r][0] * di; o.y = acc[r][1] * di;
            o.z = acc[r][2] * di; o.w = acc[r][3] * di;
            *reinterpret_cast<float4*>(&H[(size_t)row * M + col0]) = o;
        }
    }
}

// K=64, M=1: one 64-lane wave per node, shuffle-reduce; epilogue * dinv.
__global__ void gemm_k64_m1(const float* __restrict__ X, const float* __restrict__ W,
                            const float* __restrict__ dinv, float* __restrict__ H, int N) {
    int gtid = blockIdx.x * blockDim.x + threadIdx.x;
    int n = gtid >> 6;
    int lane = threadIdx.x & 63;
    if (n >= N) return;
    float v = X[(size_t)n * 64 + lane] * W[lane];
#pragma unroll
    for (int off = 32; off > 0; off >>= 1) v += __shfl_down(v, off);
    if (lane == 0) H[n] = v * dinv[n];
}

// M=128 aggregation: one wave per node. Lane half h gathers neighbor 2j+h with a
// float4 (sub = lane&31 covers 128 floats across 32 lanes). 8 rows in flight.
// All shfls wave-uniform.
__global__ void __launch_bounds__(256) agg_csr128(const int* __restrict__ rowptr,
                                                  const int* __restrict__ csr_src,
                                                  const float* __restrict__ dinv,
                                                  const float* __restrict__ Hs,
                                                  const float* __restrict__ bias,
                                                  float* __restrict__ A, int N) {
    int wid = threadIdx.x >> 6;
    int lane = threadIdx.x & 63;
    int n = blockIdx.x * 4 + wid;
    if (n >= N) return;
    int half = lane >> 5, sub = lane & 31;
    const float4* H4 = reinterpret_cast<const float4*>(Hs);  // row stride 32
    float4 acc = make_float4(0.f, 0.f, 0.f, 0.f);
    if (half == 0) acc = H4[(size_t)n * 32 + sub];            // self (already * dinv[n])
    int beg = rowptr[n], end = rowptr[n + 1];
    for (int j0 = beg; j0 < end; j0 += 64) {
        int cnt = min(64, end - j0);
        int idxv = (lane < cnt) ? csr_src[j0 + lane] : 0;
        int j = 0;
        for (; j + 8 <= cnt; j += 8) {   // 4 pair-loads = 8 rows in flight
            int s0 = __shfl(idxv, j + half);
            int s1 = __shfl(idxv, j + 2 + half);
            int s2 = __shfl(idxv, j + 4 + half);
            int s3 = __shfl(idxv, j + 6 + half);
            float4 v0 = H4[(size_t)s0 * 32 + sub];
            float4 v1 = H4[(size_t)s1 * 32 + sub];
            float4 v2 = H4[(size_t)s2 * 32 + sub];
            float4 v3 = H4[(size_t)s3 * 32 + sub];
            acc.x += v0.x + v1.x + v2.x + v3.x;
            acc.y += v0.y + v1.y + v2.y + v3.y;
            acc.z += v0.z + v1.z + v2.z + v3.z;
            acc.w += v0.w + v1.w + v2.w + v3.w;
        }
        for (; j + 2 <= cnt; j += 2) {
            int s = __shfl(idxv, j + half);
            float4 v = H4[(size_t)s * 32 + sub];
            acc.x += v.x; acc.y += v.y; acc.z += v.z; acc.w += v.w;
        }
        if (j < cnt) {                   // odd leftover: shfl by ALL lanes, add in half 0
            int s = __shfl(idxv, j);
            if (half == 0) {
                float4 v = H4[(size_t)s * 32 + sub];
                acc.x += v.x; acc.y += v.y; acc.z += v.z; acc.w += v.w;
            }
        }
    }
    acc.x += __shfl_down(acc.x, 32);
    acc.y += __shfl_down(acc.y, 32);
    acc.z += __shfl_down(acc.z, 32);
    acc.w += __shfl_down(acc.w, 32);
    if (half == 0) {
        float di = dinv[n];
        float4 b = reinterpret_cast<const float4*>(bias)[sub];
        float4 o;
        o.x = tanhf(acc.x * di + b.x);
        o.y = tanhf(acc.y * di + b.y);
        o.z = tanhf(acc.z * di + b.z);
        o.w = tanhf(acc.w * di + b.w);
        reinterpret_cast<float4*>(A)[(size_t)n * 32 + sub] = o;
    }
}

// M=64 aggregation: one wave per node. Lane group g (16 lanes) gathers neighbor
// 4j+g with a float4. Tail: shfl with CLAMPED source lane under uniform exec,
// predicated add (R4's divergent-shfl bug fixed here).
__global__ void __launch_bounds__(256) agg_csr64(const int* __restrict__ rowptr,
                                                 const int* __restrict__ csr_src,
                                                 const float* __restrict__ dinv,
                                                 const float* __restrict__ Hs,
                                                 const float* __restrict__ bias,
                                                 float* __restrict__ A, int N) {
    int wid = threadIdx.x >> 6;
    int lane = threadIdx.x & 63;
    int n = blockIdx.x * 4 + wid;
    if (n >= N) return;
    int grp = lane >> 4, sub = lane & 15;
    const float4* H4 = reinterpret_cast<const float4*>(Hs);  // row stride 16
    float4 acc = make_float4(0.f, 0.f, 0.f, 0.f);
    if (grp == 0) acc = H4[(size_t)n * 16 + sub];
    int beg = rowptr[n], end = rowptr[n + 1];
    for (int j0 = beg; j0 < end; j0 += 64) {
        int cnt = min(64, end - j0);
        int idxv = (lane < cnt) ? csr_src[j0 + lane] : 0;
        int j = 0;
        for (; j + 8 <= cnt; j += 8) {   // 2 quad-loads = 8 rows in flight
            int s0 = __shfl(idxv, j + grp);
            int s1 = __shfl(idxv, j + 4 + grp);
            float4 v0 = H4[(size_t)s0 * 16 + sub];
            float4 v1 = H4[(size_t)s1 * 16 + sub];
            acc.x += v0.x + v1.x;
            acc.y += v0.y + v1.y;
            acc.z += v0.z + v1.z;
            acc.w += v0.w + v1.w;
        }
        for (; j + 4 <= cnt; j += 4) {
            int s = __shfl(idxv, j + grp);
            float4 v = H4[(size_t)s * 16 + sub];
            acc.x += v.x; acc.y += v.y; acc.z += v.z; acc.w += v.w;
        }
        int r = cnt - j;                 // 0..3, wave-uniform
        if (r > 0) {                     // uniform branch: shfl by ALL lanes
            int s = __shfl(idxv, j + min(grp, r - 1));  // clamped source lane
            if (grp < r) {               // predicated add only
                float4 v = H4[(size_t)s * 16 + sub];
                acc.x += v.x; acc.y += v.y; acc.z += v.z; acc.w += v.w;
            }
        }
    }
    acc.x += __shfl_xor(acc.x, 16);
    acc.y += __shfl_xor(acc.y, 16);
    acc.z += __shfl_xor(acc.z, 16);
    acc.w += __shfl_xor(acc.w, 16);
    acc.x += __shfl_xor(acc.x, 32);
    acc.y += __shfl_xor(acc.y, 32);
    acc.z += __shfl_xor(acc.z, 32);
    acc.w += __shfl_xor(acc.w, 32);
    if (lane < 16) {
        float di = dinv[n];
        float4 b = reinterpret_cast<const float4*>(bias)[sub];
        float4 o;
        o.x = tanhf(acc.x * di + b.x);
        o.y = tanhf(acc.y * di + b.y);
        o.z = tanhf(acc.z * di + b.z);
        o.w = tanhf(acc.w * di + b.w);
        reinterpret_cast<float4*>(A)[(size_t)n * 16 + sub] = o;
    }
}

// M=1 aggregation: one wave per node, lanes parallel over neighbors, shfl-reduce.
__global__ void __launch_bounds__(256) agg_csr_m1(const int* __restrict__ rowptr,
                                                  const int* __restrict__ csr_src,
                                                  const float* __restrict__ dinv,
                                                  const float* __restrict__ Hs,
                                                  const float* __restrict__ bias,
                                                  float* __restrict__ A, int N) {
    int wid = threadIdx.x >> 6;
    int lane = threadIdx.x & 63;
    int n = blockIdx.x * 4 + wid;
    if (n >= N) return;
    int beg = rowptr[n], end = rowptr[n + 1];
    float acc = 0.0f;
    for (int j = beg + lane; j < end; j += 64) acc += Hs[csr_src[j]];
#pragma unroll
    for (int off = 32; off > 0; off >>= 1) acc += __shfl_down(acc, off);
    if (lane == 0) A[n] = tanhf((acc + Hs[n]) * dinv[n] + bias[0]);
}

__global__ void dot_reduce(const float* __restrict__ h, const float* __restrict__ w,
                           float* __restrict__ partials, int N) {
    float acc = 0.0f;
    for (int i = blockIdx.x * blockDim.x + threadIdx.x; i < N; i += gridDim.x * blockDim.x)
        acc += h[i] * w[i];
#pragma unroll
    for (int off = 32; off > 0; off >>= 1) acc += __shfl_down(acc, off);
    __shared__ float sm[4];
    int lane = threadIdx.x & 63, wid = threadIdx.x >> 6;
    if (lane == 0) sm[wid] = acc;
    __syncthreads();
    if (threadIdx.x == 0) partials[blockIdx.x] = sm[0] + sm[1] + sm[2] + sm[3];
}

__global__ void final_sum(const float* __restrict__ partials, int B,
                          const float* __restrict__ b4, float* __restrict__ out) {
    float acc = 0.0f;
    for (int i = threadIdx.x; i < B; i += blockDim.x) acc += partials[i];
#pragma unroll
    for (int off = 32; off > 0; off >>= 1) acc += __shfl_down(acc, off);
    __shared__ float sm[4];
    int lane = threadIdx.x & 63, wid = threadIdx.x >> 6;
    if (lane == 0) sm[wid] = acc;
    __syncthreads();
    if (threadIdx.x == 0) out[0] = sm[0] + sm[1] + sm[2] + sm[3] + b4[0];
}

extern "C" void kernel_launch(void* const* d_in, const int* in_sizes, int n_in,
                              void* d_out, int out_size, void* d_ws, size_t ws_size,
                              hipStream_t stream) {
    const float* x  = (const float*)d_in[0];
    const int*   ei = (const int*)d_in[1];
    const float* W1 = (const float*)d_in[2];
    const float* b1 = (const float*)d_in[3];
    const float* W2 = (const float*)d_in[4];
    const float* b2 = (const float*)d_in[5];
    const float* W3 = (const float*)d_in[6];
    const float* b3 = (const float*)d_in[7];
    const float* W4 = (const float*)d_in[8];
    const float* b4 = (const float*)d_in[9];

    const int N = in_sizes[0] / 128;   // 50000
    const int E = in_sizes[1] / 2;     // 800000
    const int* src = ei;
    const int* dst = ei + E;

    const int nscan = (N + SCAN_B - 1) / SCAN_B;

    // Workspace layout; bufA/bufB 256 B-aligned so float4 accesses are aligned.
    float* base = (float*)d_ws;
    size_t off = 0;
    auto alloc = [&](size_t cnt, size_t align_f) -> float* {
        off = (off + align_f - 1) / align_f * align_f;
        float* p = base + off;
        off += cnt;
        return p;
    };
    float* dinv  = alloc(N, 1);
    int* deg     = (int*)alloc(N, 1);
    int* incl    = (int*)alloc(N, 1);
    int* bsums   = (int*)alloc(256, 1);
    int* rowptr  = (int*)alloc(N + 1, 1);
    int* cursor  = (int*)alloc(N, 1);
    int* csr_src = (int*)alloc(E, 1);
    float* bufA  = alloc((size_t)N * 128, 64);   // 256 B aligned
    float* bufB  = alloc((size_t)N * 128, 64);   // 256 B aligned
    float* partials = alloc(256, 64);

    const int nblkN = (N + BLOCK - 1) / BLOCK;
    const int nblkE = (E + BLOCK - 1) / BLOCK;
    const int ngemm = (N + 63) / 64;
    const int nwave = (N + 3) / 4;             // wave-per-node grids

    // --- degrees + CSR build ---
    hipMemsetAsync(deg, 0, (size_t)N * sizeof(int), stream);
    deg_hist<<<nblkE, BLOCK, 0, stream>>>(dst, deg, E);
    dinv_kernel<<<nblkN, BLOCK, 0, stream>>>(deg, dinv, N);
    scan_blocks<<<nscan, SCAN_B, 0, stream>>>(deg, incl, bsums, N);
    scan_partials<<<1, SCAN_B, 0, stream>>>(bsums, nscan);
    finalize_rowptr<<<nblkN, BLOCK, 0, stream>>>(deg, incl, bsums, rowptr, cursor, N);
    fill_csr<<<nblkE, BLOCK, 0, stream>>>(src, dst, cursor, csr_src, E);

    // --- layer 1: 128 -> 128 ---
    gemm_tiled<128, 128><<<ngemm, 256, 0, stream>>>(x, W1, dinv, bufA, N);
    agg_csr128<<<nwave, 256, 0, stream>>>(rowptr, csr_src, dinv, bufA, b1, bufB, N);

    // --- layer 2: 128 -> 64 ---
    gemm_tiled<128, 64><<<ngemm, 256, 0, stream>>>(bufB, W2, dinv, bufA, N);
    agg_csr64<<<nwave, 256, 0, stream>>>(rowptr, csr_src, dinv, bufA, b2, bufB, N);

    // --- layer 3: 64 -> 1 ---
    gemm_k64_m1<<<(N + 3) / 4, BLOCK, 0, stream>>>(bufB, W3, dinv, bufA, N);
    agg_csr_m1<<<nwave, 256, 0, stream>>>(rowptr, csr_src, dinv, bufA, b3, bufB, N);

    // --- head: out = W4 . h + b4 ---
    dot_reduce<<<256, BLOCK, 0, stream>>>(bufB, W4, partials, N);
    final_sum<<<1, BLOCK, 0, stream>>>(partials, 256, b4, (float*)d_out);
}